// Round 4
// baseline (1568.200 us; speedup 1.0000x reference)
//
#include <hip/hip_runtime.h>
#include <cstdint>

#define B_    4
#define T_    2048
#define DIM_  1024
#define H_    16
#define N_    64
#define BT_   8192

typedef float f32x2 __attribute__((ext_vector_type(2)));
typedef float f32x4 __attribute__((ext_vector_type(4)));
typedef short bf16x8 __attribute__((ext_vector_type(8)));
typedef unsigned short ushort_t;
typedef unsigned int uint32;

__device__ __forceinline__ float silu_f(float v) {
    return v / (1.f + __expf(-v));
}
__device__ __forceinline__ float tanh_f(float v) {
    return 1.f - 2.f / (__expf(2.f * v) + 1.f);
}
__device__ __forceinline__ ushort_t f2bf(float f) {
    uint32 u = __float_as_uint(f);
    return (ushort_t)((u + 0x7fffu + ((u >> 16) & 1u)) >> 16);   // RNE
}
// async global->LDS, 16B per lane; lds base must be wave-uniform
__device__ __forceinline__ void glds16(const void* g, void* l) {
    __builtin_amdgcn_global_load_lds(
        (const __attribute__((address_space(1))) void*)g,
        (__attribute__((address_space(3))) void*)l, 16, 0, 0);
}

// -------------------------------------------------------------------------
// K0: f32 -> bf16 conversion (grid covers n8 = n/8 elements of 8)
// -------------------------------------------------------------------------
__global__ __launch_bounds__(256) void cvt_kernel(
    const float* __restrict__ src, ushort_t* __restrict__ dst, int n8)
{
    int i = blockIdx.x * 256 + threadIdx.x;
    if (i >= n8) return;
    float4 a = ((const float4*)src)[i * 2];
    float4 b = ((const float4*)src)[i * 2 + 1];
    uint4 o;
    o.x = (uint32)f2bf(a.x) | ((uint32)f2bf(a.y) << 16);
    o.y = (uint32)f2bf(a.z) | ((uint32)f2bf(a.w) << 16);
    o.z = (uint32)f2bf(b.x) | ((uint32)f2bf(b.y) << 16);
    o.w = (uint32)f2bf(b.z) | ((uint32)f2bf(b.w) << 16);
    ((uint4*)dst)[i] = o;
}

// -------------------------------------------------------------------------
// K1: xz = X @ Win^T (M=8192,N=2048,K=1024) bf16 MFMA, 128x128 tile, BK=32.
// (unchanged from R3)
// -------------------------------------------------------------------------
__global__ __launch_bounds__(256) void gemm_in_kernel(
    const ushort_t* __restrict__ xw,    // [8192][1024] bf16
    const ushort_t* __restrict__ Winb,  // [2048][1024] bf16
    const float*    __restrict__ Wx,    // [16][64][64] f32
    ushort_t*       __restrict__ pg)    // [B,H,T,N] x2: [2i]=px, [2i+1]=gate
{
    __shared__ __align__(16) ushort_t Ab[128 * 32];
    __shared__ __align__(16) ushort_t Bb[128 * 32];
    __shared__ __align__(16) ushort_t Sb[128][136];
    __shared__ __align__(16) ushort_t WxT[2][64][72];

    const int tid  = threadIdx.x;
    const int wave = tid >> 6, lane = tid & 63;
    const int l15 = lane & 15, l4 = lane >> 4;
    const int bx = blockIdx.x;
    const int m0 = blockIdx.y * 128;
    const int n0 = bx * 128;
    const int wr = wave >> 1, wc = wave & 1;
    const bool xhalf = (bx < 8);

    if (xhalf) {
        for (int q = tid; q < 8192; q += 256) {
            int hh = q >> 12, rem = q & 4095, i = rem >> 6, jj = rem & 63;
            WxT[hh][jj][i] = f2bf(Wx[(((bx << 1) + hh) << 12) + (i << 6) + jj]);
        }
    }

    const f32x4 zero4 = {0.f, 0.f, 0.f, 0.f};
    f32x4 acc[4][4];
    #pragma unroll
    for (int mi = 0; mi < 4; ++mi)
        #pragma unroll
        for (int ni = 0; ni < 4; ++ni)
            acc[mi][ni] = zero4;

    const int rowL = tid >> 2;
    const int chL  = tid & 3;
    const ushort_t* gA0 = xw   + (size_t)(m0 + rowL) * 1024 + (chL << 3);
    const ushort_t* gA1 = xw   + (size_t)(m0 + 64 + rowL) * 1024 + (chL << 3);
    const ushort_t* gB0 = Winb + (size_t)(n0 + rowL) * 1024 + (chL << 3);
    const ushort_t* gB1 = Winb + (size_t)(n0 + 64 + rowL) * 1024 + (chL << 3);
    ushort_t* lA0 = Ab + wave * 512;
    ushort_t* lA1 = Ab + 2048 + wave * 512;
    ushort_t* lB0 = Bb + wave * 512;
    ushort_t* lB1 = Bb + 2048 + wave * 512;

    for (int k0 = 0; k0 < 1024; k0 += 32) {
        __syncthreads();
        glds16(gA0 + k0, lA0);
        glds16(gA1 + k0, lA1);
        glds16(gB0 + k0, lB0);
        glds16(gB1 + k0, lB1);
        asm volatile("s_waitcnt vmcnt(0)");
        __syncthreads();
        bf16x8 aF[4], bF[4];
        #pragma unroll
        for (int mi = 0; mi < 4; ++mi)
            aF[mi] = *(const bf16x8*)&Ab[(wr * 64 + mi * 16 + l15) * 32 + l4 * 8];
        #pragma unroll
        for (int ni = 0; ni < 4; ++ni)
            bF[ni] = *(const bf16x8*)&Bb[(wc * 64 + ni * 16 + l15) * 32 + l4 * 8];
        #pragma unroll
        for (int mi = 0; mi < 4; ++mi)
            #pragma unroll
            for (int ni = 0; ni < 4; ++ni)
                acc[mi][ni] = __builtin_amdgcn_mfma_f32_16x16x32_bf16(
                    aF[mi], bF[ni], acc[mi][ni], 0, 0, 0);
    }

    if (!xhalf) {
        const int h = bx - 8;
        #pragma unroll
        for (int mi = 0; mi < 4; ++mi)
            #pragma unroll
            for (int ni = 0; ni < 4; ++ni) {
                int col = (h << 7) + wc * 64 + ni * 16 + l15;
                int hh = col >> 6, n = col & 63;
                #pragma unroll
                for (int r = 0; r < 4; ++r) {
                    int row = m0 + wr * 64 + mi * 16 + l4 * 4 + r;
                    int b = row >> 11, t = row & 2047;
                    size_t idx = ((size_t)((b << 4) + hh) * 2048 + t) * 64 + n;
                    pg[idx * 2 + 1] = f2bf(silu_f(acc[mi][ni][r]));
                }
            }
    } else {
        __syncthreads();
        #pragma unroll
        for (int mi = 0; mi < 4; ++mi)
            #pragma unroll
            for (int ni = 0; ni < 4; ++ni) {
                int col = wc * 64 + ni * 16 + l15;
                #pragma unroll
                for (int r = 0; r < 4; ++r) {
                    int row = wr * 64 + mi * 16 + l4 * 4 + r;
                    Sb[row][col] = f2bf(silu_f(acc[mi][ni][r]));
                }
            }
        __syncthreads();
        #pragma unroll
        for (int hh = 0; hh < 2; ++hh) {
            f32x4 acc2[2][4];
            #pragma unroll
            for (int mf = 0; mf < 2; ++mf)
                #pragma unroll
                for (int nf = 0; nf < 4; ++nf)
                    acc2[mf][nf] = zero4;
            #pragma unroll
            for (int ks = 0; ks < 2; ++ks) {
                bf16x8 a2[2], b2[4];
                #pragma unroll
                for (int mf = 0; mf < 2; ++mf)
                    a2[mf] = *(const bf16x8*)&Sb[wave * 32 + mf * 16 + l15]
                                                [hh * 64 + ks * 32 + l4 * 8];
                #pragma unroll
                for (int nf = 0; nf < 4; ++nf)
                    b2[nf] = *(const bf16x8*)&WxT[hh][nf * 16 + l15][ks * 32 + l4 * 8];
                #pragma unroll
                for (int mf = 0; mf < 2; ++mf)
                    #pragma unroll
                    for (int nf = 0; nf < 4; ++nf)
                        acc2[mf][nf] = __builtin_amdgcn_mfma_f32_16x16x32_bf16(
                            a2[mf], b2[nf], acc2[mf][nf], 0, 0, 0);
            }
            const int hg = (bx << 1) + hh;
            #pragma unroll
            for (int mf = 0; mf < 2; ++mf)
                #pragma unroll
                for (int nf = 0; nf < 4; ++nf) {
                    int jj = nf * 16 + l15;
                    #pragma unroll
                    for (int r = 0; r < 4; ++r) {
                        int row = m0 + wave * 32 + mf * 16 + l4 * 4 + r;
                        int b = row >> 11, t = row & 2047;
                        size_t idx = ((size_t)((b << 4) + hg) * 2048 + t) * 64 + jj;
                        pg[idx * 2] = f2bf(acc2[mf][nf][r]);
                    }
                }
        }
    }
}

// -------------------------------------------------------------------------
// K2: sequential Elman scan, 2 recurrences per wave (same h, b=2b',2b'+1 ->
// shared W_h registers). Two independent latency chains interleave; loads
// block-batched 8-deep double-buffered; outputs staged in LDS and flushed
// as one dwordx4 burst per pair per 8 steps (stores never block load waits).
// grid = 32, block = 64
// -------------------------------------------------------------------------
__global__ __launch_bounds__(64) void scan_kernel(
    const uint32* __restrict__ pg,   // [B,H,T,N] packed: lo=px, hi=gate
    ushort_t* __restrict__ og,       // out bf16 [B,H,T,N]
    const float* __restrict__ Wh,
    const float* __restrict__ bias,
    const float* __restrict__ h0,
    float* __restrict__ hfin)
{
    const int q = blockIdx.x;            // 0..31
    const int h = q & 15, bp = q >> 4;   // head, batch-pair
    const int bhA = ((bp << 1) + 0) * 16 + h;
    const int bhB = ((bp << 1) + 1) * 16 + h;
    const int j = threadIdx.x;

    __shared__ float shA[64];
    __shared__ float shB[64];
    __shared__ ushort_t stA[512];
    __shared__ ushort_t stB[512];

    f32x2 w2[32];
    #pragma unroll
    for (int i = 0; i < 32; ++i) {
        w2[i].x = Wh[(h << 12) + ((2 * i) << 6) + j];
        w2[i].y = Wh[(h << 12) + ((2 * i + 1) << 6) + j];
    }
    const float bj = bias[(h << 6) + j];

    shA[j] = h0[(bhA << 6) + j];
    shB[j] = h0[(bhB << 6) + j];
    __syncthreads();

    const uint32* pgA = pg + ((size_t)bhA << 17);
    const uint32* pgB = pg + ((size_t)bhB << 17);
    ushort_t* ogA = og + ((size_t)bhA << 17);
    ushort_t* ogB = og + ((size_t)bhB << 17);

    uint32 eA[8], eB[8], oA[8], oB[8];
    #pragma unroll
    for (int u = 0; u < 8; ++u) {
        eA[u] = pgA[(u << 6) + j];
        eB[u] = pgB[(u << 6) + j];
    }

    float hnA = 0.f, hnB = 0.f;

#define SCAN_STEP(SH, ST, V, HN)                                          \
    do {                                                                  \
        const uint32 v_ = (V);                                            \
        const float px_ = __uint_as_float(v_ << 16);                      \
        const float g_  = __uint_as_float(v_ & 0xffff0000u);              \
        f32x2 a0 = {px_ + bj, 0.f};                                       \
        f32x2 a1 = {0.f, 0.f}, a2 = {0.f, 0.f}, a3 = {0.f, 0.f};          \
        _Pragma("unroll")                                                 \
        for (int i_ = 0; i_ < 8; ++i_) {                                  \
            float4 hv0 = *(const float4*)&SH[(i_ << 3) + 0];              \
            float4 hv1 = *(const float4*)&SH[(i_ << 3) + 4];              \
            f32x2 h01 = {hv0.x, hv0.y}, h23 = {hv0.z, hv0.w};             \
            f32x2 h45 = {hv1.x, hv1.y}, h67 = {hv1.z, hv1.w};             \
            a0 = h01 * w2[(i_ << 2) + 0] + a0;                            \
            a1 = h23 * w2[(i_ << 2) + 1] + a1;                            \
            a2 = h45 * w2[(i_ << 2) + 2] + a2;                            \
            a3 = h67 * w2[(i_ << 2) + 3] + a3;                            \
        }                                                                 \
        float a_ = ((a0.x + a0.y) + (a1.x + a1.y)) +                      \
                   ((a2.x + a2.y) + (a3.x + a3.y));                       \
        HN = tanh_f(a_);                                                  \
        ST[(u << 6) + j] = f2bf(HN * g_);                                 \
        SH[j] = HN;                                                       \
    } while (0)

    for (int k = 0; k < 128; ++k) {
        const int t0 = k << 4;

        // prefetch steps t0+8 .. t0+15 into o-buffers
        #pragma unroll
        for (int u = 0; u < 8; ++u) {
            oA[u] = pgA[((t0 + 8 + u) << 6) + j];
            oB[u] = pgB[((t0 + 8 + u) << 6) + j];
        }
        // process steps t0 .. t0+7 from e-buffers
        #pragma unroll
        for (int u = 0; u < 8; ++u) {
            SCAN_STEP(shA, stA, eA[u], hnA);
            SCAN_STEP(shB, stB, eB[u], hnB);
        }
        // burst-flush block t0 (one dwordx4 per pair)
        {
            int4 wa = *(const int4*)&stA[j << 3];
            int4 wb = *(const int4*)&stB[j << 3];
            *(int4*)(ogA + ((size_t)t0 << 6) + (j << 3)) = wa;
            *(int4*)(ogB + ((size_t)t0 << 6) + (j << 3)) = wb;
        }
        // prefetch steps t0+16 .. t0+23 into e-buffers (clamped at tail)
        #pragma unroll
        for (int u = 0; u < 8; ++u) {
            int tt = t0 + 16 + u;
            if (tt > T_ - 1) tt = T_ - 1;
            eA[u] = pgA[(tt << 6) + j];
            eB[u] = pgB[(tt << 6) + j];
        }
        // process steps t0+8 .. t0+15 from o-buffers
        #pragma unroll
        for (int u = 0; u < 8; ++u) {
            SCAN_STEP(shA, stA, oA[u], hnA);
            SCAN_STEP(shB, stB, oB[u], hnB);
        }
        // burst-flush block t0+8
        {
            int4 wa = *(const int4*)&stA[j << 3];
            int4 wb = *(const int4*)&stB[j << 3];
            *(int4*)(ogA + ((size_t)(t0 + 8) << 6) + (j << 3)) = wa;
            *(int4*)(ogB + ((size_t)(t0 + 8) << 6) + (j << 3)) = wb;
        }
    }
#undef SCAN_STEP

    hfin[(bhA << 6) + j] = hnA;
    hfin[(bhB << 6) + j] = hnB;
}

// -------------------------------------------------------------------------
// K3: out = og @ Wout^T (M=8192,N=1024,K=1024) bf16 MFMA, 128x128, BK=32.
// (unchanged from R3)
// -------------------------------------------------------------------------
__global__ __launch_bounds__(256) void gemm_out_kernel(
    const ushort_t* __restrict__ og,     // [B,H,T,N] bf16
    const ushort_t* __restrict__ Woutb,  // [1024][1024] bf16
    float* __restrict__ out)             // [8192][1024] f32
{
    __shared__ __align__(16) ushort_t Ab[128 * 32];
    __shared__ __align__(16) ushort_t Bb[128 * 32];

    const int tid  = threadIdx.x;
    const int wave = tid >> 6, lane = tid & 63;
    const int l15 = lane & 15, l4 = lane >> 4;
    const int m0 = blockIdx.y * 128;
    const int n0 = blockIdx.x * 128;
    const int wr = wave >> 1, wc = wave & 1;

    const f32x4 zero4 = {0.f, 0.f, 0.f, 0.f};
    f32x4 acc[4][4];
    #pragma unroll
    for (int mi = 0; mi < 4; ++mi)
        #pragma unroll
        for (int ni = 0; ni < 4; ++ni)
            acc[mi][ni] = zero4;

    const int rowL = tid >> 2;
    const int chL  = tid & 3;
    const int mA0 = m0 + rowL,       bA0 = mA0 >> 11, tA0 = mA0 & 2047;
    const int mA1 = m0 + 64 + rowL,  bA1 = mA1 >> 11, tA1 = mA1 & 2047;
    const ushort_t* gB0 = Woutb + (size_t)(n0 + rowL) * 1024 + (chL << 3);
    const ushort_t* gB1 = Woutb + (size_t)(n0 + 64 + rowL) * 1024 + (chL << 3);
    ushort_t* lA0 = Ab + wave * 512;
    ushort_t* lA1 = Ab + 2048 + wave * 512;
    ushort_t* lB0 = Bb + wave * 512;
    ushort_t* lB1 = Bb + 2048 + wave * 512;

    for (int k0 = 0; k0 < 1024; k0 += 32) {
        const int he = k0 >> 6, ke = (k0 & 63) + (chL << 3);
        const ushort_t* gA0 = og + ((size_t)((bA0 << 4) + he) * 2048 + tA0) * 64 + ke;
        const ushort_t* gA1 = og + ((size_t)((bA1 << 4) + he) * 2048 + tA1) * 64 + ke;
        __syncthreads();
        glds16(gA0, lA0);
        glds16(gA1, lA1);
        glds16(gB0 + k0, lB0);
        glds16(gB1 + k0, lB1);
        asm volatile("s_waitcnt vmcnt(0)");
        __syncthreads();
        bf16x8 aF[4], bF[4];
        #pragma unroll
        for (int mi = 0; mi < 4; ++mi)
            aF[mi] = *(const bf16x8*)&Ab[(wr * 64 + mi * 16 + l15) * 32 + l4 * 8];
        #pragma unroll
        for (int ni = 0; ni < 4; ++ni)
            bF[ni] = *(const bf16x8*)&Bb[(wc * 64 + ni * 16 + l15) * 32 + l4 * 8];
        #pragma unroll
        for (int mi = 0; mi < 4; ++mi)
            #pragma unroll
            for (int ni = 0; ni < 4; ++ni)
                acc[mi][ni] = __builtin_amdgcn_mfma_f32_16x16x32_bf16(
                    aF[mi], bF[ni], acc[mi][ni], 0, 0, 0);
    }

    #pragma unroll
    for (int mi = 0; mi < 4; ++mi)
        #pragma unroll
        for (int ni = 0; ni < 4; ++ni) {
            int d = n0 + wc * 64 + ni * 16 + l15;
            #pragma unroll
            for (int r = 0; r < 4; ++r) {
                int row = m0 + wr * 64 + mi * 16 + l4 * 4 + r;
                out[(size_t)row * 1024 + d] = acc[mi][ni][r];
            }
        }
}

// -------------------------------------------------------------------------
extern "C" void kernel_launch(void* const* d_in, const int* in_sizes, int n_in,
                              void* d_out, int out_size, void* d_ws, size_t ws_size,
                              hipStream_t stream)
{
    const float* x    = (const float*)d_in[0];
    const float* h0   = (const float*)d_in[1];
    const float* Win  = (const float*)d_in[2];
    const float* Wx   = (const float*)d_in[3];
    const float* Wh   = (const float*)d_in[4];
    const float* bias = (const float*)d_in[5];
    const float* Wout = (const float*)d_in[6];

    float* out  = (float*)d_out;
    float* hfin = out + (size_t)BT_ * DIM_;

    char* ws = (char*)d_ws;
    ushort_t* pg    = (ushort_t*)(ws);                      // 32 MB packed px/gate
    ushort_t* xw    = (ushort_t*)(ws + 33554432);           // 16 MB bf16 x
    ushort_t* ogb   = xw;                                   // og aliases xw (dead after K1)
    ushort_t* Winb  = (ushort_t*)(ws + 50331648);           // 4 MB
    ushort_t* Woutb = (ushort_t*)(ws + 54525952);           // 2 MB

    cvt_kernel<<<4096, 256, 0, stream>>>(x, xw, 1048576);
    cvt_kernel<<<1024, 256, 0, stream>>>(Win, Winb, 262144);
    cvt_kernel<<<512, 256, 0, stream>>>(Wout, Woutb, 131072);

    gemm_in_kernel<<<dim3(16, 64), 256, 0, stream>>>(xw, Winb, Wx, pg);
    scan_kernel<<<32, 64, 0, stream>>>((const uint32*)pg, ogb, Wh, bias, h0, hfin);
    gemm_out_kernel<<<dim3(8, 64), 256, 0, stream>>>(ogb, Woutb, out);
}

// Round 5
// 871.131 us; speedup vs baseline: 1.8002x; 1.8002x over previous
//
#include <hip/hip_runtime.h>
#include <cstdint>

#define B_    4
#define T_    2048
#define DIM_  1024
#define H_    16
#define N_    64
#define BT_   8192

typedef float f32x2 __attribute__((ext_vector_type(2)));
typedef float f32x4 __attribute__((ext_vector_type(4)));
typedef short bf16x8 __attribute__((ext_vector_type(8)));
typedef unsigned short ushort_t;
typedef unsigned int uint32;

__device__ __forceinline__ float silu_f(float v) {
    return v / (1.f + __expf(-v));
}
__device__ __forceinline__ float tanh_f(float v) {
    return 1.f - 2.f / (__expf(2.f * v) + 1.f);
}
__device__ __forceinline__ ushort_t f2bf(float f) {
    uint32 u = __float_as_uint(f);
    return (ushort_t)((u + 0x7fffu + ((u >> 16) & 1u)) >> 16);   // RNE
}
// async global->LDS, 16B per lane; lds base must be wave-uniform
__device__ __forceinline__ void glds16(const void* g, void* l) {
    __builtin_amdgcn_global_load_lds(
        (const __attribute__((address_space(1))) void*)g,
        (__attribute__((address_space(3))) void*)l, 16, 0, 0);
}

// -------------------------------------------------------------------------
// K0: f32 -> bf16 conversion (grid covers n8 = n/8 elements of 8)
// -------------------------------------------------------------------------
__global__ __launch_bounds__(256) void cvt_kernel(
    const float* __restrict__ src, ushort_t* __restrict__ dst, int n8)
{
    int i = blockIdx.x * 256 + threadIdx.x;
    if (i >= n8) return;
    float4 a = ((const float4*)src)[i * 2];
    float4 b = ((const float4*)src)[i * 2 + 1];
    uint4 o;
    o.x = (uint32)f2bf(a.x) | ((uint32)f2bf(a.y) << 16);
    o.y = (uint32)f2bf(a.z) | ((uint32)f2bf(a.w) << 16);
    o.z = (uint32)f2bf(b.x) | ((uint32)f2bf(b.y) << 16);
    o.w = (uint32)f2bf(b.z) | ((uint32)f2bf(b.w) << 16);
    ((uint4*)dst)[i] = o;
}

// -------------------------------------------------------------------------
// K1: xz = X @ Win^T (M=8192,N=2048,K=1024) bf16 MFMA, 128x128 tile, BK=32.
// (unchanged from R3)
// -------------------------------------------------------------------------
__global__ __launch_bounds__(256) void gemm_in_kernel(
    const ushort_t* __restrict__ xw,    // [8192][1024] bf16
    const ushort_t* __restrict__ Winb,  // [2048][1024] bf16
    const float*    __restrict__ Wx,    // [16][64][64] f32
    ushort_t*       __restrict__ pg)    // [B,H,T,N] x2: [2i]=px, [2i+1]=gate
{
    __shared__ __align__(16) ushort_t Ab[128 * 32];
    __shared__ __align__(16) ushort_t Bb[128 * 32];
    __shared__ __align__(16) ushort_t Sb[128][136];
    __shared__ __align__(16) ushort_t WxT[2][64][72];

    const int tid  = threadIdx.x;
    const int wave = tid >> 6, lane = tid & 63;
    const int l15 = lane & 15, l4 = lane >> 4;
    const int bx = blockIdx.x;
    const int m0 = blockIdx.y * 128;
    const int n0 = bx * 128;
    const int wr = wave >> 1, wc = wave & 1;
    const bool xhalf = (bx < 8);

    if (xhalf) {
        for (int q = tid; q < 8192; q += 256) {
            int hh = q >> 12, rem = q & 4095, i = rem >> 6, jj = rem & 63;
            WxT[hh][jj][i] = f2bf(Wx[(((bx << 1) + hh) << 12) + (i << 6) + jj]);
        }
    }

    const f32x4 zero4 = {0.f, 0.f, 0.f, 0.f};
    f32x4 acc[4][4];
    #pragma unroll
    for (int mi = 0; mi < 4; ++mi)
        #pragma unroll
        for (int ni = 0; ni < 4; ++ni)
            acc[mi][ni] = zero4;

    const int rowL = tid >> 2;
    const int chL  = tid & 3;
    const ushort_t* gA0 = xw   + (size_t)(m0 + rowL) * 1024 + (chL << 3);
    const ushort_t* gA1 = xw   + (size_t)(m0 + 64 + rowL) * 1024 + (chL << 3);
    const ushort_t* gB0 = Winb + (size_t)(n0 + rowL) * 1024 + (chL << 3);
    const ushort_t* gB1 = Winb + (size_t)(n0 + 64 + rowL) * 1024 + (chL << 3);
    ushort_t* lA0 = Ab + wave * 512;
    ushort_t* lA1 = Ab + 2048 + wave * 512;
    ushort_t* lB0 = Bb + wave * 512;
    ushort_t* lB1 = Bb + 2048 + wave * 512;

    for (int k0 = 0; k0 < 1024; k0 += 32) {
        __syncthreads();
        glds16(gA0 + k0, lA0);
        glds16(gA1 + k0, lA1);
        glds16(gB0 + k0, lB0);
        glds16(gB1 + k0, lB1);
        asm volatile("s_waitcnt vmcnt(0)");
        __syncthreads();
        bf16x8 aF[4], bF[4];
        #pragma unroll
        for (int mi = 0; mi < 4; ++mi)
            aF[mi] = *(const bf16x8*)&Ab[(wr * 64 + mi * 16 + l15) * 32 + l4 * 8];
        #pragma unroll
        for (int ni = 0; ni < 4; ++ni)
            bF[ni] = *(const bf16x8*)&Bb[(wc * 64 + ni * 16 + l15) * 32 + l4 * 8];
        #pragma unroll
        for (int mi = 0; mi < 4; ++mi)
            #pragma unroll
            for (int ni = 0; ni < 4; ++ni)
                acc[mi][ni] = __builtin_amdgcn_mfma_f32_16x16x32_bf16(
                    aF[mi], bF[ni], acc[mi][ni], 0, 0, 0);
    }

    if (!xhalf) {
        const int h = bx - 8;
        #pragma unroll
        for (int mi = 0; mi < 4; ++mi)
            #pragma unroll
            for (int ni = 0; ni < 4; ++ni) {
                int col = (h << 7) + wc * 64 + ni * 16 + l15;
                int hh = col >> 6, n = col & 63;
                #pragma unroll
                for (int r = 0; r < 4; ++r) {
                    int row = m0 + wr * 64 + mi * 16 + l4 * 4 + r;
                    int b = row >> 11, t = row & 2047;
                    size_t idx = ((size_t)((b << 4) + hh) * 2048 + t) * 64 + n;
                    pg[idx * 2 + 1] = f2bf(silu_f(acc[mi][ni][r]));
                }
            }
    } else {
        __syncthreads();
        #pragma unroll
        for (int mi = 0; mi < 4; ++mi)
            #pragma unroll
            for (int ni = 0; ni < 4; ++ni) {
                int col = wc * 64 + ni * 16 + l15;
                #pragma unroll
                for (int r = 0; r < 4; ++r) {
                    int row = wr * 64 + mi * 16 + l4 * 4 + r;
                    Sb[row][col] = f2bf(silu_f(acc[mi][ni][r]));
                }
            }
        __syncthreads();
        #pragma unroll
        for (int hh = 0; hh < 2; ++hh) {
            f32x4 acc2[2][4];
            #pragma unroll
            for (int mf = 0; mf < 2; ++mf)
                #pragma unroll
                for (int nf = 0; nf < 4; ++nf)
                    acc2[mf][nf] = zero4;
            #pragma unroll
            for (int ks = 0; ks < 2; ++ks) {
                bf16x8 a2[2], b2[4];
                #pragma unroll
                for (int mf = 0; mf < 2; ++mf)
                    a2[mf] = *(const bf16x8*)&Sb[wave * 32 + mf * 16 + l15]
                                                [hh * 64 + ks * 32 + l4 * 8];
                #pragma unroll
                for (int nf = 0; nf < 4; ++nf)
                    b2[nf] = *(const bf16x8*)&WxT[hh][nf * 16 + l15][ks * 32 + l4 * 8];
                #pragma unroll
                for (int mf = 0; mf < 2; ++mf)
                    #pragma unroll
                    for (int nf = 0; nf < 4; ++nf)
                        acc2[mf][nf] = __builtin_amdgcn_mfma_f32_16x16x32_bf16(
                            a2[mf], b2[nf], acc2[mf][nf], 0, 0, 0);
            }
            const int hg = (bx << 1) + hh;
            #pragma unroll
            for (int mf = 0; mf < 2; ++mf)
                #pragma unroll
                for (int nf = 0; nf < 4; ++nf) {
                    int jj = nf * 16 + l15;
                    #pragma unroll
                    for (int r = 0; r < 4; ++r) {
                        int row = m0 + wave * 32 + mf * 16 + l4 * 4 + r;
                        int b = row >> 11, t = row & 2047;
                        size_t idx = ((size_t)((b << 4) + hg) * 2048 + t) * 64 + jj;
                        pg[idx * 2] = f2bf(acc2[mf][nf][r]);
                    }
                }
        }
    }
}

// -------------------------------------------------------------------------
// K2: sequential Elman scan (R3 structure: 1 chain per wave, grid 64,
// packed pg loads, 8-deep ring prefetch). ONE change vs R3:
// __launch_bounds__(64, 1) -> min 1 wave/EU -> full 512-VGPR budget so the
// 64 W_h values stay register-resident instead of being re-loaded from
// global every timestep (R3 compiled to 52 VGPRs < 64 needed for W alone).
// -------------------------------------------------------------------------
__global__ __launch_bounds__(64, 1) void scan_kernel(
    const uint32* __restrict__ pg,   // [B,H,T,N] packed: lo=px, hi=gate
    ushort_t* __restrict__ og,       // out bf16 [B,H,T,N]
    const float* __restrict__ Wh,
    const float* __restrict__ bias,
    const float* __restrict__ h0,
    float* __restrict__ hfin)
{
    const int bh = blockIdx.x;
    const int h = bh & 15;
    const int j = threadIdx.x;
    __shared__ float sh[64];

    f32x2 w2[32];
    #pragma unroll
    for (int i = 0; i < 32; ++i) {
        w2[i].x = Wh[(h << 12) + ((2 * i) << 6) + j];
        w2[i].y = Wh[(h << 12) + ((2 * i + 1) << 6) + j];
    }
    const float bj = bias[(h << 6) + j];

    sh[j] = h0[(bh << 6) + j];
    __syncthreads();

    const uint32* pg_p = pg + ((size_t)bh << 17);
    ushort_t* og_p = og + ((size_t)bh << 17);

    uint32 buf[8];
    #pragma unroll
    for (int u = 0; u < 8; ++u)
        buf[u] = pg_p[(u << 6) + j];

    float hn = 0.f;
    for (int t0 = 0; t0 < T_; t0 += 8) {
        #pragma unroll
        for (int u = 0; u < 8; ++u) {
            const int t = t0 + u;
            const uint32 v = buf[u];
            int tn = t + 8;
            if (tn > T_ - 1) tn = T_ - 1;
            buf[u] = pg_p[(tn << 6) + j];

            const float px = __uint_as_float(v << 16);
            const float g  = __uint_as_float(v & 0xffff0000u);

            f32x2 a0 = {px + bj, 0.f};
            f32x2 a1 = {0.f, 0.f}, a2 = {0.f, 0.f}, a3 = {0.f, 0.f};
            #pragma unroll
            for (int i = 0; i < 8; ++i) {
                float4 hv0 = *(const float4*)&sh[(i << 3) + 0];
                float4 hv1 = *(const float4*)&sh[(i << 3) + 4];
                f32x2 h01 = {hv0.x, hv0.y}, h23 = {hv0.z, hv0.w};
                f32x2 h45 = {hv1.x, hv1.y}, h67 = {hv1.z, hv1.w};
                a0 = h01 * w2[(i << 2) + 0] + a0;
                a1 = h23 * w2[(i << 2) + 1] + a1;
                a2 = h45 * w2[(i << 2) + 2] + a2;
                a3 = h67 * w2[(i << 2) + 3] + a3;
            }
            float a = ((a0.x + a0.y) + (a1.x + a1.y)) +
                      ((a2.x + a2.y) + (a3.x + a3.y));
            hn = tanh_f(a);
            og_p[(t << 6) + j] = f2bf(hn * g);

            __builtin_amdgcn_wave_barrier();
            sh[j] = hn;
            __builtin_amdgcn_wave_barrier();
        }
    }
    hfin[(bh << 6) + j] = hn;
}

// -------------------------------------------------------------------------
// K3: out = og @ Wout^T (M=8192,N=1024,K=1024) bf16 MFMA, 128x128, BK=32.
// (unchanged from R3)
// -------------------------------------------------------------------------
__global__ __launch_bounds__(256) void gemm_out_kernel(
    const ushort_t* __restrict__ og,     // [B,H,T,N] bf16
    const ushort_t* __restrict__ Woutb,  // [1024][1024] bf16
    float* __restrict__ out)             // [8192][1024] f32
{
    __shared__ __align__(16) ushort_t Ab[128 * 32];
    __shared__ __align__(16) ushort_t Bb[128 * 32];

    const int tid  = threadIdx.x;
    const int wave = tid >> 6, lane = tid & 63;
    const int l15 = lane & 15, l4 = lane >> 4;
    const int m0 = blockIdx.y * 128;
    const int n0 = blockIdx.x * 128;
    const int wr = wave >> 1, wc = wave & 1;

    const f32x4 zero4 = {0.f, 0.f, 0.f, 0.f};
    f32x4 acc[4][4];
    #pragma unroll
    for (int mi = 0; mi < 4; ++mi)
        #pragma unroll
        for (int ni = 0; ni < 4; ++ni)
            acc[mi][ni] = zero4;

    const int rowL = tid >> 2;
    const int chL  = tid & 3;
    const int mA0 = m0 + rowL,       bA0 = mA0 >> 11, tA0 = mA0 & 2047;
    const int mA1 = m0 + 64 + rowL,  bA1 = mA1 >> 11, tA1 = mA1 & 2047;
    const ushort_t* gB0 = Woutb + (size_t)(n0 + rowL) * 1024 + (chL << 3);
    const ushort_t* gB1 = Woutb + (size_t)(n0 + 64 + rowL) * 1024 + (chL << 3);
    ushort_t* lA0 = Ab + wave * 512;
    ushort_t* lA1 = Ab + 2048 + wave * 512;
    ushort_t* lB0 = Bb + wave * 512;
    ushort_t* lB1 = Bb + 2048 + wave * 512;

    for (int k0 = 0; k0 < 1024; k0 += 32) {
        const int he = k0 >> 6, ke = (k0 & 63) + (chL << 3);
        const ushort_t* gA0 = og + ((size_t)((bA0 << 4) + he) * 2048 + tA0) * 64 + ke;
        const ushort_t* gA1 = og + ((size_t)((bA1 << 4) + he) * 2048 + tA1) * 64 + ke;
        __syncthreads();
        glds16(gA0, lA0);
        glds16(gA1, lA1);
        glds16(gB0 + k0, lB0);
        glds16(gB1 + k0, lB1);
        asm volatile("s_waitcnt vmcnt(0)");
        __syncthreads();
        bf16x8 aF[4], bF[4];
        #pragma unroll
        for (int mi = 0; mi < 4; ++mi)
            aF[mi] = *(const bf16x8*)&Ab[(wr * 64 + mi * 16 + l15) * 32 + l4 * 8];
        #pragma unroll
        for (int ni = 0; ni < 4; ++ni)
            bF[ni] = *(const bf16x8*)&Bb[(wc * 64 + ni * 16 + l15) * 32 + l4 * 8];
        #pragma unroll
        for (int mi = 0; mi < 4; ++mi)
            #pragma unroll
            for (int ni = 0; ni < 4; ++ni)
                acc[mi][ni] = __builtin_amdgcn_mfma_f32_16x16x32_bf16(
                    aF[mi], bF[ni], acc[mi][ni], 0, 0, 0);
    }

    #pragma unroll
    for (int mi = 0; mi < 4; ++mi)
        #pragma unroll
        for (int ni = 0; ni < 4; ++ni) {
            int d = n0 + wc * 64 + ni * 16 + l15;
            #pragma unroll
            for (int r = 0; r < 4; ++r) {
                int row = m0 + wr * 64 + mi * 16 + l4 * 4 + r;
                out[(size_t)row * 1024 + d] = acc[mi][ni][r];
            }
        }
}

// -------------------------------------------------------------------------
extern "C" void kernel_launch(void* const* d_in, const int* in_sizes, int n_in,
                              void* d_out, int out_size, void* d_ws, size_t ws_size,
                              hipStream_t stream)
{
    const float* x    = (const float*)d_in[0];
    const float* h0   = (const float*)d_in[1];
    const float* Win  = (const float*)d_in[2];
    const float* Wx   = (const float*)d_in[3];
    const float* Wh   = (const float*)d_in[4];
    const float* bias = (const float*)d_in[5];
    const float* Wout = (const float*)d_in[6];

    float* out  = (float*)d_out;
    float* hfin = out + (size_t)BT_ * DIM_;

    char* ws = (char*)d_ws;
    ushort_t* pg    = (ushort_t*)(ws);                      // 32 MB packed px/gate
    ushort_t* xw    = (ushort_t*)(ws + 33554432);           // 16 MB bf16 x
    ushort_t* ogb   = xw;                                   // og aliases xw (dead after K1)
    ushort_t* Winb  = (ushort_t*)(ws + 50331648);           // 4 MB
    ushort_t* Woutb = (ushort_t*)(ws + 54525952);           // 2 MB

    cvt_kernel<<<4096, 256, 0, stream>>>(x, xw, 1048576);
    cvt_kernel<<<1024, 256, 0, stream>>>(Win, Winb, 262144);
    cvt_kernel<<<512, 256, 0, stream>>>(Wout, Woutb, 131072);

    gemm_in_kernel<<<dim3(16, 64), 256, 0, stream>>>(xw, Winb, Wx, pg);
    scan_kernel<<<64, 64, 0, stream>>>((const uint32*)pg, ogb, Wh, bias, h0, hfin);
    gemm_out_kernel<<<dim3(8, 64), 256, 0, stream>>>(ogb, Woutb, out);
}

// Round 7
// 586.078 us; speedup vs baseline: 2.6758x; 1.4864x over previous
//
#include <hip/hip_runtime.h>
#include <cstdint>

#define B_    4
#define T_    2048
#define DIM_  1024
#define H_    16
#define N_    64
#define BT_   8192

typedef float f32x2 __attribute__((ext_vector_type(2)));
typedef float f32x4 __attribute__((ext_vector_type(4)));
typedef short bf16x8 __attribute__((ext_vector_type(8)));
typedef unsigned short ushort_t;
typedef unsigned int uint32;

__device__ __forceinline__ float silu_f(float v) {
    return v / (1.f + __expf(-v));
}
__device__ __forceinline__ float tanh_f(float v) {
    return 1.f - 2.f / (__expf(2.f * v) + 1.f);
}
__device__ __forceinline__ ushort_t f2bf(float f) {
    uint32 u = __float_as_uint(f);
    return (ushort_t)((u + 0x7fffu + ((u >> 16) & 1u)) >> 16);   // RNE
}
// async global->LDS, 16B per lane; lds base must be wave-uniform
__device__ __forceinline__ void glds16(const void* g, void* l) {
    __builtin_amdgcn_global_load_lds(
        (const __attribute__((address_space(1))) void*)g,
        (__attribute__((address_space(3))) void*)l, 16, 0, 0);
}

// -------------------------------------------------------------------------
// K0: f32 -> bf16 conversion (grid covers n8 = n/8 elements of 8)
// -------------------------------------------------------------------------
__global__ __launch_bounds__(256) void cvt_kernel(
    const float* __restrict__ src, ushort_t* __restrict__ dst, int n8)
{
    int i = blockIdx.x * 256 + threadIdx.x;
    if (i >= n8) return;
    float4 a = ((const float4*)src)[i * 2];
    float4 b = ((const float4*)src)[i * 2 + 1];
    uint4 o;
    o.x = (uint32)f2bf(a.x) | ((uint32)f2bf(a.y) << 16);
    o.y = (uint32)f2bf(a.z) | ((uint32)f2bf(a.w) << 16);
    o.z = (uint32)f2bf(b.x) | ((uint32)f2bf(b.y) << 16);
    o.w = (uint32)f2bf(b.z) | ((uint32)f2bf(b.w) << 16);
    ((uint4*)dst)[i] = o;
}

// -------------------------------------------------------------------------
// K1: xz = X @ Win^T (M=8192,N=2048,K=1024) bf16 MFMA, 128x128 tile, BK=32.
// Writes packed pg: [2i]=px bf16, [2i+1]=gate bf16 (R5-proven layout).
// grid = (16, 64), block = 256
// -------------------------------------------------------------------------
__global__ __launch_bounds__(256) void gemm_in_kernel(
    const ushort_t* __restrict__ xw,    // [8192][1024] bf16
    const ushort_t* __restrict__ Winb,  // [2048][1024] bf16
    const float*    __restrict__ Wx,    // [16][64][64] f32
    ushort_t*       __restrict__ pg)    // [B,H,T,N] x2: [2i]=px, [2i+1]=gate
{
    __shared__ __align__(16) ushort_t Ab[128 * 32];
    __shared__ __align__(16) ushort_t Bb[128 * 32];
    __shared__ __align__(16) ushort_t Sb[128][136];
    __shared__ __align__(16) ushort_t WxT[2][64][72];

    const int tid  = threadIdx.x;
    const int wave = tid >> 6, lane = tid & 63;
    const int l15 = lane & 15, l4 = lane >> 4;
    const int bx = blockIdx.x;
    const int m0 = blockIdx.y * 128;
    const int n0 = bx * 128;
    const int wr = wave >> 1, wc = wave & 1;
    const bool xhalf = (bx < 8);

    if (xhalf) {
        for (int q = tid; q < 8192; q += 256) {
            int hh = q >> 12, rem = q & 4095, i = rem >> 6, jj = rem & 63;
            WxT[hh][jj][i] = f2bf(Wx[(((bx << 1) + hh) << 12) + (i << 6) + jj]);
        }
    }

    const f32x4 zero4 = {0.f, 0.f, 0.f, 0.f};
    f32x4 acc[4][4];
    #pragma unroll
    for (int mi = 0; mi < 4; ++mi)
        #pragma unroll
        for (int ni = 0; ni < 4; ++ni)
            acc[mi][ni] = zero4;

    const int rowL = tid >> 2;
    const int chL  = tid & 3;
    const ushort_t* gA0 = xw   + (size_t)(m0 + rowL) * 1024 + (chL << 3);
    const ushort_t* gA1 = xw   + (size_t)(m0 + 64 + rowL) * 1024 + (chL << 3);
    const ushort_t* gB0 = Winb + (size_t)(n0 + rowL) * 1024 + (chL << 3);
    const ushort_t* gB1 = Winb + (size_t)(n0 + 64 + rowL) * 1024 + (chL << 3);
    ushort_t* lA0 = Ab + wave * 512;
    ushort_t* lA1 = Ab + 2048 + wave * 512;
    ushort_t* lB0 = Bb + wave * 512;
    ushort_t* lB1 = Bb + 2048 + wave * 512;

    for (int k0 = 0; k0 < 1024; k0 += 32) {
        __syncthreads();
        glds16(gA0 + k0, lA0);
        glds16(gA1 + k0, lA1);
        glds16(gB0 + k0, lB0);
        glds16(gB1 + k0, lB1);
        asm volatile("s_waitcnt vmcnt(0)");
        __syncthreads();
        bf16x8 aF[4], bF[4];
        #pragma unroll
        for (int mi = 0; mi < 4; ++mi)
            aF[mi] = *(const bf16x8*)&Ab[(wr * 64 + mi * 16 + l15) * 32 + l4 * 8];
        #pragma unroll
        for (int ni = 0; ni < 4; ++ni)
            bF[ni] = *(const bf16x8*)&Bb[(wc * 64 + ni * 16 + l15) * 32 + l4 * 8];
        #pragma unroll
        for (int mi = 0; mi < 4; ++mi)
            #pragma unroll
            for (int ni = 0; ni < 4; ++ni)
                acc[mi][ni] = __builtin_amdgcn_mfma_f32_16x16x32_bf16(
                    aF[mi], bF[ni], acc[mi][ni], 0, 0, 0);
    }

    if (!xhalf) {
        const int h = bx - 8;
        #pragma unroll
        for (int mi = 0; mi < 4; ++mi)
            #pragma unroll
            for (int ni = 0; ni < 4; ++ni) {
                int col = (h << 7) + wc * 64 + ni * 16 + l15;
                int hh = col >> 6, n = col & 63;
                #pragma unroll
                for (int r = 0; r < 4; ++r) {
                    int row = m0 + wr * 64 + mi * 16 + l4 * 4 + r;
                    int b = row >> 11, t = row & 2047;
                    size_t idx = ((size_t)((b << 4) + hh) * 2048 + t) * 64 + n;
                    pg[idx * 2 + 1] = f2bf(silu_f(acc[mi][ni][r]));
                }
            }
    } else {
        __syncthreads();
        #pragma unroll
        for (int mi = 0; mi < 4; ++mi)
            #pragma unroll
            for (int ni = 0; ni < 4; ++ni) {
                int col = wc * 64 + ni * 16 + l15;
                #pragma unroll
                for (int r = 0; r < 4; ++r) {
                    int row = wr * 64 + mi * 16 + l4 * 4 + r;
                    Sb[row][col] = f2bf(silu_f(acc[mi][ni][r]));
                }
            }
        __syncthreads();
        #pragma unroll
        for (int hh = 0; hh < 2; ++hh) {
            f32x4 acc2[2][4];
            #pragma unroll
            for (int mf = 0; mf < 2; ++mf)
                #pragma unroll
                for (int nf = 0; nf < 4; ++nf)
                    acc2[mf][nf] = zero4;
            #pragma unroll
            for (int ks = 0; ks < 2; ++ks) {
                bf16x8 a2[2], b2[4];
                #pragma unroll
                for (int mf = 0; mf < 2; ++mf)
                    a2[mf] = *(const bf16x8*)&Sb[wave * 32 + mf * 16 + l15]
                                                [hh * 64 + ks * 32 + l4 * 8];
                #pragma unroll
                for (int nf = 0; nf < 4; ++nf)
                    b2[nf] = *(const bf16x8*)&WxT[hh][nf * 16 + l15][ks * 32 + l4 * 8];
                #pragma unroll
                for (int mf = 0; mf < 2; ++mf)
                    #pragma unroll
                    for (int nf = 0; nf < 4; ++nf)
                        acc2[mf][nf] = __builtin_amdgcn_mfma_f32_16x16x32_bf16(
                            a2[mf], b2[nf], acc2[mf][nf], 0, 0, 0);
            }
            const int hg = (bx << 1) + hh;
            #pragma unroll
            for (int mf = 0; mf < 2; ++mf)
                #pragma unroll
                for (int nf = 0; nf < 4; ++nf) {
                    int jj = nf * 16 + l15;
                    #pragma unroll
                    for (int r = 0; r < 4; ++r) {
                        int row = m0 + wave * 32 + mf * 16 + l4 * 4 + r;
                        int b = row >> 11, t = row & 2047;
                        size_t idx = ((size_t)((b << 4) + hg) * 2048 + t) * 64 + jj;
                        pg[idx * 2] = f2bf(acc2[mf][nf][r]);
                    }
                }
        }
    }
}

// -------------------------------------------------------------------------
// K2: sequential Elman scan. R5 base (packed pg dword loads, 8-deep ring
// prefetch, LDS h-broadcast) with ONE change: per-step output goes to LDS
// (ds_write_b16, off the vmcnt queue) and is flushed as one
// global_store_dwordx4 per lane per 8 steps. Tests whether the per-step
// 2-byte global store in the in-order vmcnt queue caused the R1->R2
// regression (639 -> 903 cyc/step).
// grid = 64, block = 64
// -------------------------------------------------------------------------
__global__ __launch_bounds__(64, 1) void scan_kernel(
    const uint32* __restrict__ pg,   // [B,H,T,N] packed: lo=px, hi=gate
    ushort_t* __restrict__ og,       // out bf16 [B,H,T,N]
    const float* __restrict__ Wh,
    const float* __restrict__ bias,
    const float* __restrict__ h0,
    float* __restrict__ hfin)
{
    const int bh = blockIdx.x;
    const int h = bh & 15;
    const int j = threadIdx.x;
    __shared__ float sh[64];
    __shared__ ushort_t stg[512];    // 8 steps x 64 lanes staged output

    f32x2 w2[32];
    #pragma unroll
    for (int i = 0; i < 32; ++i) {
        w2[i].x = Wh[(h << 12) + ((2 * i) << 6) + j];
        w2[i].y = Wh[(h << 12) + ((2 * i + 1) << 6) + j];
    }
    const float bj = bias[(h << 6) + j];

    sh[j] = h0[(bh << 6) + j];
    __syncthreads();

    const uint32* pg_p = pg + ((size_t)bh << 17);
    ushort_t* og_p = og + ((size_t)bh << 17);

    uint32 buf[8];
    #pragma unroll
    for (int u = 0; u < 8; ++u)
        buf[u] = pg_p[(u << 6) + j];

    float hn = 0.f;
    for (int t0 = 0; t0 < T_; t0 += 8) {
        #pragma unroll
        for (int u = 0; u < 8; ++u) {
            const int t = t0 + u;
            const uint32 v = buf[u];
            int tn = t + 8;
            if (tn > T_ - 1) tn = T_ - 1;
            buf[u] = pg_p[(tn << 6) + j];

            const float px = __uint_as_float(v << 16);
            const float g  = __uint_as_float(v & 0xffff0000u);

            f32x2 a0 = {px + bj, 0.f};
            f32x2 a1 = {0.f, 0.f}, a2 = {0.f, 0.f}, a3 = {0.f, 0.f};
            #pragma unroll
            for (int i = 0; i < 8; ++i) {
                float4 hv0 = *(const float4*)&sh[(i << 3) + 0];
                float4 hv1 = *(const float4*)&sh[(i << 3) + 4];
                f32x2 h01 = {hv0.x, hv0.y}, h23 = {hv0.z, hv0.w};
                f32x2 h45 = {hv1.x, hv1.y}, h67 = {hv1.z, hv1.w};
                a0 = h01 * w2[(i << 2) + 0] + a0;
                a1 = h23 * w2[(i << 2) + 1] + a1;
                a2 = h45 * w2[(i << 2) + 2] + a2;
                a3 = h67 * w2[(i << 2) + 3] + a3;
            }
            float a = ((a0.x + a0.y) + (a1.x + a1.y)) +
                      ((a2.x + a2.y) + (a3.x + a3.y));
            hn = tanh_f(a);

            stg[(u << 6) + j] = f2bf(hn * g);   // LDS stage (off vmcnt path)

            __builtin_amdgcn_wave_barrier();
            sh[j] = hn;
            __builtin_amdgcn_wave_barrier();
        }
        // burst-flush 8 staged steps: 1KB contiguous, one dwordx4 per lane
        {
            int4 wv = *(const int4*)&stg[j << 3];
            *(int4*)(og_p + ((size_t)t0 << 6) + (j << 3)) = wv;
        }
    }
    hfin[(bh << 6) + j] = hn;
}

// -------------------------------------------------------------------------
// K3: out = og @ Wout^T (M=8192,N=1024,K=1024) bf16 MFMA, 128x128, BK=32.
// (unchanged)
// -------------------------------------------------------------------------
__global__ __launch_bounds__(256) void gemm_out_kernel(
    const ushort_t* __restrict__ og,     // [B,H,T,N] bf16
    const ushort_t* __restrict__ Woutb,  // [1024][1024] bf16
    float* __restrict__ out)             // [8192][1024] f32
{
    __shared__ __align__(16) ushort_t Ab[128 * 32];
    __shared__ __align__(16) ushort_t Bb[128 * 32];

    const int tid  = threadIdx.x;
    const int wave = tid >> 6, lane = tid & 63;
    const int l15 = lane & 15, l4 = lane >> 4;
    const int m0 = blockIdx.y * 128;
    const int n0 = blockIdx.x * 128;
    const int wr = wave >> 1, wc = wave & 1;

    const f32x4 zero4 = {0.f, 0.f, 0.f, 0.f};
    f32x4 acc[4][4];
    #pragma unroll
    for (int mi = 0; mi < 4; ++mi)
        #pragma unroll
        for (int ni = 0; ni < 4; ++ni)
            acc[mi][ni] = zero4;

    const int rowL = tid >> 2;
    const int chL  = tid & 3;
    const int mA0 = m0 + rowL,       bA0 = mA0 >> 11, tA0 = mA0 & 2047;
    const int mA1 = m0 + 64 + rowL,  bA1 = mA1 >> 11, tA1 = mA1 & 2047;
    const ushort_t* gB0 = Woutb + (size_t)(n0 + rowL) * 1024 + (chL << 3);
    const ushort_t* gB1 = Woutb + (size_t)(n0 + 64 + rowL) * 1024 + (chL << 3);
    ushort_t* lA0 = Ab + wave * 512;
    ushort_t* lA1 = Ab + 2048 + wave * 512;
    ushort_t* lB0 = Bb + wave * 512;
    ushort_t* lB1 = Bb + 2048 + wave * 512;

    for (int k0 = 0; k0 < 1024; k0 += 32) {
        const int he = k0 >> 6, ke = (k0 & 63) + (chL << 3);
        const ushort_t* gA0 = og + ((size_t)((bA0 << 4) + he) * 2048 + tA0) * 64 + ke;
        const ushort_t* gA1 = og + ((size_t)((bA1 << 4) + he) * 2048 + tA1) * 64 + ke;
        __syncthreads();
        glds16(gA0, lA0);
        glds16(gA1, lA1);
        glds16(gB0 + k0, lB0);
        glds16(gB1 + k0, lB1);
        asm volatile("s_waitcnt vmcnt(0)");
        __syncthreads();
        bf16x8 aF[4], bF[4];
        #pragma unroll
        for (int mi = 0; mi < 4; ++mi)
            aF[mi] = *(const bf16x8*)&Ab[(wr * 64 + mi * 16 + l15) * 32 + l4 * 8];
        #pragma unroll
        for (int ni = 0; ni < 4; ++ni)
            bF[ni] = *(const bf16x8*)&Bb[(wc * 64 + ni * 16 + l15) * 32 + l4 * 8];
        #pragma unroll
        for (int mi = 0; mi < 4; ++mi)
            #pragma unroll
            for (int ni = 0; ni < 4; ++ni)
                acc[mi][ni] = __builtin_amdgcn_mfma_f32_16x16x32_bf16(
                    aF[mi], bF[ni], acc[mi][ni], 0, 0, 0);
    }

    #pragma unroll
    for (int mi = 0; mi < 4; ++mi)
        #pragma unroll
        for (int ni = 0; ni < 4; ++ni) {
            int d = n0 + wc * 64 + ni * 16 + l15;
            #pragma unroll
            for (int r = 0; r < 4; ++r) {
                int row = m0 + wr * 64 + mi * 16 + l4 * 4 + r;
                out[(size_t)row * 1024 + d] = acc[mi][ni][r];
            }
        }
}

// -------------------------------------------------------------------------
extern "C" void kernel_launch(void* const* d_in, const int* in_sizes, int n_in,
                              void* d_out, int out_size, void* d_ws, size_t ws_size,
                              hipStream_t stream)
{
    const float* x    = (const float*)d_in[0];
    const float* h0   = (const float*)d_in[1];
    const float* Win  = (const float*)d_in[2];
    const float* Wx   = (const float*)d_in[3];
    const float* Wh   = (const float*)d_in[4];
    const float* bias = (const float*)d_in[5];
    const float* Wout = (const float*)d_in[6];

    float* out  = (float*)d_out;
    float* hfin = out + (size_t)BT_ * DIM_;

    // ws layout (54 MB total; R5-proven):
    char* ws = (char*)d_ws;
    ushort_t* pg    = (ushort_t*)(ws);                      // 32 MB packed px/gate
    ushort_t* xw    = (ushort_t*)(ws + 33554432);           // 16 MB bf16 x
    ushort_t* ogb   = xw;                                   // og aliases xw (dead after K1)
    ushort_t* Winb  = (ushort_t*)(ws + 50331648);           //  4 MB
    ushort_t* Woutb = (ushort_t*)(ws + 54525952);           //  2 MB

    cvt_kernel<<<4096, 256, 0, stream>>>(x, xw, 1048576);
    cvt_kernel<<<1024, 256, 0, stream>>>(Win, Winb, 262144);
    cvt_kernel<<<512, 256, 0, stream>>>(Wout, Woutb, 131072);

    gemm_in_kernel<<<dim3(16, 64), 256, 0, stream>>>(xw, Winb, Wx, pg);
    scan_kernel<<<64, 64, 0, stream>>>((const uint32*)pg, ogb, Wh, bias, h0, hfin);
    gemm_out_kernel<<<dim3(8, 64), 256, 0, stream>>>(ogb, Woutb, out);
}